// Round 1
// 1265.613 us; speedup vs baseline: 2.7439x; 2.7439x over previous
//
#include <hip/hip_runtime.h>
#include <math.h>

// Problem constants
#define Bq 1024
#define Dd 512
#define Nn 131072
#define Kk 16
#define Mm 32    // candidates rescored in f64 per row
#define CPR 2048 // candidates per row (256 lanes x top-8)

// Output layout (flat concat, reference return order)
#define OUT_SC  0
#define OUT_IDX (Bq * Kk)
#define OUT_SEQ (2 * Bq * Kk)
#define OUT_LAB (2 * Bq * Kk + Bq * Kk * Dd)

using bf16x8 = __attribute__((ext_vector_type(8))) __bf16;
using f32x4  = __attribute__((ext_vector_type(4))) float;
using u16x8  = __attribute__((ext_vector_type(8))) unsigned short;
using u16x4  = __attribute__((ext_vector_type(4))) unsigned short;

__device__ __forceinline__ unsigned short f2bf(float f) {  // RNE f32->bf16
  unsigned u = __builtin_bit_cast(unsigned, f);
  return (unsigned short)((u + 0x7FFFu + ((u >> 16) & 1u)) >> 16);
}
__device__ __forceinline__ float bf2f(unsigned short b) {
  return __builtin_bit_cast(float, (unsigned)b << 16);
}

// async global->LDS, 16B per lane (dst must be wave-uniform base + lane*16)
#define GLD16(gp, lp)                                                   \
  __builtin_amdgcn_global_load_lds(                                     \
      (const __attribute__((address_space(1))) unsigned int*)(gp),      \
      (__attribute__((address_space(3))) unsigned int*)(lp), 16, 0, 0)

// ---------------------------------------------------------------------------
// Kernel 1: L2-normalize queries -> bf16, pre-swizzled for LDS A-tile.
// Within each 128B (64-element) kt-group, 16B chunk c stored at c ^ (row&7)
// so global_load_lds (linear) + XOR-read gives conflict-free ds_read_b128.
// ---------------------------------------------------------------------------
__global__ __launch_bounds__(256) void k_norm(const float* __restrict__ q,
                                              unsigned short* __restrict__ qb) {
  const int row = blockIdx.x;
  const int t = threadIdx.x;
  const float v0 = q[row * Dd + t];
  const float v1 = q[row * Dd + t + 256];
  float ss = v0 * v0 + v1 * v1;
#pragma unroll
  for (int m = 32; m >= 1; m >>= 1) ss += __shfl_xor(ss, m);
  __shared__ float wsum[4];
  if ((t & 63) == 0) wsum[t >> 6] = ss;
  __syncthreads();
  const float inv = rsqrtf(wsum[0] + wsum[1] + wsum[2] + wsum[3]);
  const int r7 = row & 7;
  const int k0 = t;
  const int p0 = (k0 & ~0x38) | ((((k0 >> 3) & 7) ^ r7) << 3);
  qb[row * Dd + p0] = f2bf(v0 * inv);
  const int k1 = t + 256;
  const int p1 = (k1 & ~0x38) | ((((k1 >> 3) & 7) ^ r7) << 3);
  qb[row * Dd + p1] = f2bf(v1 * inv);
}

// ---------------------------------------------------------------------------
// Kernel 2: bf16 MFMA GEMM: sims[chunk rows][N] (bf16, lane-permuted cols).
// Block = 256 rows x 128 cols, 256 thr = 4 waves (2 rowgroups x 2 colgroups),
// wave = 128r x 64c = 8x4 frags of mfma_f32_16x16x32_bf16. K-loop BK=64.
// A: global_load_lds from pre-swizzled qb. B: fp32 w -> bf16, transposed
// in-register (k-pairs) into padded [128][72] LDS with XOR k-swizzle.
// sims permuted store: col' = n0 + colg*64 + m*4 + cf (8B-coalesced).
// ---------------------------------------------------------------------------
__global__ __launch_bounds__(256, 2) void k_gemm(
    const unsigned short* __restrict__ qb, const float* __restrict__ w,
    unsigned short* __restrict__ sims, int m0) {
  __shared__ __align__(16) unsigned short As[256 * 64];  // 32 KB
  __shared__ __align__(16) unsigned short Bs[128 * 72];  // 18 KB (pad+swz)
  const int t = threadIdx.x;
  const int l = t & 63;
  const int wv = t >> 6;
  const int m = l & 15;
  const int g = l >> 4;
  const int rowg = wv >> 1;
  const int colg = wv & 1;
  const int rb = m0 + blockIdx.x * 256;
  const int n0 = blockIdx.y * 128;
  const int ct = t & 31, dt = t >> 5;

  f32x4 acc[8][4] = {};

  for (int kt = 0; kt < 8; kt++) {
    __syncthreads();
    // stage A: 2048 x 16B chunks, 8 per thread (qb already swizzled)
#pragma unroll
    for (int p = 0; p < 8; p++) {
      const int i = p * 256 + t;
      const int r = i >> 3, c = i & 7;
      GLD16(qb + (size_t)(rb + r) * Dd + kt * 64 + c * 8, &As[i * 8]);
    }
    // stage B: 64k x 128n fp32 -> bf16, k-major per col, XOR-swizzled
    {
      const float* src = w + (size_t)(kt * 64 + dt * 8) * Nn + n0 + ct * 4;
#pragma unroll
      for (int h = 0; h < 2; h++) {
        f32x4 f0 = *(const f32x4*)(src + (size_t)(h * 4 + 0) * Nn);
        f32x4 f1 = *(const f32x4*)(src + (size_t)(h * 4 + 1) * Nn);
        f32x4 f2 = *(const f32x4*)(src + (size_t)(h * 4 + 2) * Nn);
        f32x4 f3 = *(const f32x4*)(src + (size_t)(h * 4 + 3) * Nn);
#pragma unroll
        for (int j = 0; j < 4; j++) {
          const int col = ct * 4 + j;
          unsigned* dst =
              (unsigned*)&Bs[col * 72 + ((dt * 8) ^ ((ct & 7) << 3))];
          dst[h * 2 + 0] =
              (unsigned)f2bf(f0[j]) | ((unsigned)f2bf(f1[j]) << 16);
          dst[h * 2 + 1] =
              (unsigned)f2bf(f2[j]) | ((unsigned)f2bf(f3[j]) << 16);
        }
      }
    }
    __syncthreads();
#pragma unroll
    for (int ks = 0; ks < 2; ks++) {
      bf16x8 b[4];
#pragma unroll
      for (int cf = 0; cf < 4; cf++) {
        const int col = colg * 64 + cf * 16 + m;
        const int kpos = (ks * 32 + g * 8) ^ (((col >> 2) & 7) << 3);
        b[cf] = *(const bf16x8*)&Bs[col * 72 + kpos];
      }
#pragma unroll
      for (int rf = 0; rf < 8; rf++) {
        const int row = rowg * 128 + rf * 16 + m;
        const int cc = (ks * 4 + g) ^ (row & 7);
        const bf16x8 a = *(const bf16x8*)&As[row * 64 + cc * 8];
#pragma unroll
        for (int cf = 0; cf < 4; cf++)
          acc[rf][cf] = __builtin_amdgcn_mfma_f32_16x16x32_bf16(
              a, b[cf], acc[rf][cf], 0, 0, 0);
      }
    }
  }
  // epilogue: D row = rowg*128+rf*16+g*4+r ; true col = colg*64+cf*16+m
  // stored permuted at col' = colg*64 + m*4 + cf  (contiguous per lane)
#pragma unroll
  for (int rf = 0; rf < 8; rf++)
#pragma unroll
    for (int r = 0; r < 4; r++) {
      const int srow = blockIdx.x * 256 + rowg * 128 + rf * 16 + g * 4 + r;
      u16x4 v = {f2bf(acc[rf][0][r]), f2bf(acc[rf][1][r]),
                 f2bf(acc[rf][2][r]), f2bf(acc[rf][3][r])};
      *(u16x4*)&sims[(size_t)srow * Nn + n0 + colg * 64 + m * 4] = v;
    }
}

// ---------------------------------------------------------------------------
// Kernel 3: per-row streaming per-lane top-8 over bf16 sims.
// 256 lanes x top-8 = 2048 candidates/row in the exact cs/ci format k_final
// expects. De-permutes col' -> true col at emission. Coverage: a true top-16
// member is lost only if >=8 better values share its lane (P ~ 1e-13).
// ---------------------------------------------------------------------------
__global__ __launch_bounds__(256) void k_select(
    const unsigned short* __restrict__ sims, float* __restrict__ cs,
    int* __restrict__ ci, int m0) {
  const int srow = blockIdx.x;
  const int row = m0 + srow;
  const int t = threadIdx.x;
  const unsigned short* base = sims + (size_t)srow * Nn;
  float s[8];
  int ix[8];
#pragma unroll
  for (int q2 = 0; q2 < 8; q2++) { s[q2] = -INFINITY; ix[q2] = 0; }
  float mn = -INFINITY;
#pragma unroll 2
  for (int it = 0; it < Nn / 2048; it++) {
    const int off = it * 2048 + t * 8;
    const u16x8 v = *(const u16x8*)(base + off);
    float f[8];
#pragma unroll
    for (int j = 0; j < 8; j++) f[j] = bf2f(v[j]);
    const float vm = fmaxf(fmaxf(fmaxf(f[0], f[1]), fmaxf(f[2], f[3])),
                           fmaxf(fmaxf(f[4], f[5]), fmaxf(f[6], f[7])));
    if (vm > mn) {
#pragma unroll
      for (int j = 0; j < 8; j++) {
        if (f[j] > mn) {
          float cm = s[0];
          int cp = 0;
#pragma unroll
          for (int q2 = 1; q2 < 8; q2++)
            if (s[q2] < cm) { cm = s[q2]; cp = q2; }
#pragma unroll
          for (int q2 = 0; q2 < 8; q2++)   // static-indexed replace (no scratch)
            if (q2 == cp) { s[q2] = f[j]; ix[q2] = off + j; }
          mn = s[0];
#pragma unroll
          for (int q2 = 1; q2 < 8; q2++) mn = fminf(mn, s[q2]);
        }
      }
    }
  }
#pragma unroll
  for (int q2 = 0; q2 < 8; q2++) {
    const int cp = ix[q2];
    const int b7 = cp & 127;  // col' = colg*64 + m*4 + cf -> col = colg*64+cf*16+m
    const int col = (cp & ~127) + ((b7 >> 6) << 6) + ((b7 & 3) << 4) + ((b7 >> 2) & 15);
    cs[(size_t)row * CPR + t * 8 + q2] = s[q2];
    ci[(size_t)row * CPR + t * 8 + q2] = col;
  }
}

// ---------------------------------------------------------------------------
// Kernel 4 (UNCHANGED): per row — wave 0 extracts top-32 from LDS; per-wave
// f64 norm; waves rescore 8 candidates each in f64; wave 0 sorted top-16;
// gather. Butterflies use lane-id final tie-break (strict total order).
// ---------------------------------------------------------------------------
__global__ __launch_bounds__(256) void k_final(
    const float* __restrict__ cs, const int* __restrict__ ci,
    const float* __restrict__ label, const float* __restrict__ w,
    const float* __restrict__ q, float* __restrict__ out) {
  const int row = blockIdx.x;
  const int t = threadIdx.x;
  const int lane = t & 63;
  const int wv = t >> 6;

  __shared__ float shs[CPR];
  __shared__ int shi[CPR];
  __shared__ int sel[Mm];
  __shared__ double resc[Mm];
  __shared__ int sel16[Kk];

#pragma unroll
  for (int j = 0; j < CPR / 256; j++) {
    const int c = j * 256 + t;
    shs[c] = cs[row * CPR + c];
    shi[c] = ci[row * CPR + c] & (Nn - 1);
  }
  __syncthreads();

  if (t < 64) {
    const int seg = t * (CPR / 64);
    float bs = -INFINITY;
    int bi = 0x7fffffff;
    int bp = seg;
    for (int p = seg; p < seg + CPR / 64; p++) {
      const float v = shs[p];
      const int ix = shi[p];
      if (v > bs || (v == bs && ix < bi)) { bs = v; bi = ix; bp = p; }
    }
#pragma unroll 1
    for (int it = 0; it < Mm; it++) {
      float s = bs;
      int si = bi;
      int sl = t;
#pragma unroll
      for (int mk = 32; mk >= 1; mk >>= 1) {
        const float so = __shfl_xor(s, mk);
        const int io = __shfl_xor(si, mk);
        const int lo = __shfl_xor(sl, mk);
        if (so > s || (so == s && (io < si || (io == si && lo < sl)))) {
          s = so; si = io; sl = lo;
        }
      }
      if (t == 0) sel[it] = si & (Nn - 1);
      if (t == sl) {
        shs[bp] = -INFINITY;
        bs = -INFINITY;
        bi = 0x7fffffff;
        bp = seg;
        for (int p = seg; p < seg + CPR / 64; p++) {
          const float v = shs[p];
          const int ix = shi[p];
          if (v > bs || (v == bs && ix < bi)) { bs = v; bi = ix; bp = p; }
        }
      }
    }
  }
  __syncthreads();

  double qd[8];
#pragma unroll
  for (int j = 0; j < 8; j++) qd[j] = (double)q[row * Dd + lane * 8 + j];
  double nn = 0.0;
#pragma unroll
  for (int j = 0; j < 8; j++) nn += qd[j] * qd[j];
#pragma unroll
  for (int mk = 32; mk >= 1; mk >>= 1) nn += __shfl_xor(nn, mk);
  const double nrm = sqrt(nn);

#pragma unroll 1
  for (int i = 0; i < Mm / 4; i++) {
    const int c = wv * (Mm / 4) + i;
    const int idx = sel[c];
    double d = 0.0;
#pragma unroll
    for (int j = 0; j < 8; j++)
      d += qd[j] * (double)w[(size_t)(lane * 8 + j) * Nn + idx];
#pragma unroll
    for (int mk = 32; mk >= 1; mk >>= 1) d += __shfl_xor(d, mk);
    if (lane == 0) resc[c] = d / nrm;
  }
  __syncthreads();

  float* out_sc = out + OUT_SC;
  float* out_ix = out + OUT_IDX;
  float* out_sq = out + OUT_SEQ;
  float* out_lb = out + OUT_LAB;
  if (t < 64) {
    double s = (t < Mm) ? resc[t] : -INFINITY;
    int ix = (t < Mm) ? sel[t] : 0x7fffffff;
#pragma unroll 1
    for (int it = 0; it < Kk; it++) {
      double bs2 = s;
      int bi2 = ix;
      int bl = t;
#pragma unroll
      for (int mk = 32; mk >= 1; mk >>= 1) {
        const double so = __shfl_xor(bs2, mk);
        const int io = __shfl_xor(bi2, mk);
        const int lo = __shfl_xor(bl, mk);
        if (so > bs2 || (so == bs2 && (io < bi2 || (io == bi2 && lo < bl)))) {
          bs2 = so; bi2 = io; bl = lo;
        }
      }
      if (t == 0) {
        const int safe = bi2 & (Nn - 1);
        out_sc[row * Kk + it] = (float)bs2;
        out_ix[row * Kk + it] = (float)bi2;
        out_lb[row * Kk + it] = label[safe];
        sel16[it] = safe;
      }
      if (t == bl) { s = -INFINITY; ix = 0x7fffffff; }
    }
  }
  __syncthreads();

#pragma unroll 1
  for (int j = 0; j < Kk; j++) {
    const int idx = sel16[j];
    out_sq[(size_t)(row * Kk + j) * Dd + t] = w[(size_t)t * Nn + idx];
    out_sq[(size_t)(row * Kk + j) * Dd + t + 256] =
        w[(size_t)(t + 256) * Nn + idx];
  }
}

// ---------------------------------------------------------------------------
extern "C" void kernel_launch(void* const* d_in, const int* in_sizes, int n_in,
                              void* d_out, int out_size, void* d_ws,
                              size_t ws_size, hipStream_t stream) {
  const float* q = (const float*)d_in[0];
  const float* w = (const float*)d_in[1];
  const float* lab = (const float*)d_in[2];
  float* out = (float*)d_out;

  // workspace: qb bf16 swz (1 MB) | cs (8 MB) | ci (8 MB) | sims chunk (bf16)
  unsigned short* qb = (unsigned short*)d_ws;
  float* cs = (float*)((char*)d_ws + (size_t)Bq * Dd * 2);
  int* ci = (int*)(cs + (size_t)Bq * CPR);
  unsigned short* sims = (unsigned short*)(ci + (size_t)Bq * CPR);

  const size_t fixed = (size_t)Bq * Dd * 2 + (size_t)Bq * CPR * 8;
  int chunk = 256;  // needs ~85 MB of ws; larger chunks cut w re-reads
  if (ws_size >= fixed + (size_t)1024 * Nn * 2) chunk = 1024;
  else if (ws_size >= fixed + (size_t)512 * Nn * 2) chunk = 512;

  k_norm<<<Bq, 256, 0, stream>>>(q, qb);
  for (int m0 = 0; m0 < Bq; m0 += chunk) {
    k_gemm<<<dim3(chunk / 256, Nn / 128), 256, 0, stream>>>(qb, w, sims, m0);
    k_select<<<chunk, 256, 0, stream>>>(sims, cs, ci, m0);
  }
  k_final<<<Bq, 256, 0, stream>>>(cs, ci, lab, w, q, out);
}

// Round 2
// 953.934 us; speedup vs baseline: 3.6404x; 1.3267x over previous
//
#include <hip/hip_runtime.h>
#include <math.h>

// Problem constants
#define Bq 1024
#define Dd 512
#define Nn 131072
#define Kk 16
#define Mm 32    // candidates rescored in f64 per row
#define CPR 2048 // candidates per row (256 lanes x top-8)

// Output layout (flat concat, reference return order)
#define OUT_SC  0
#define OUT_IDX (Bq * Kk)
#define OUT_SEQ (2 * Bq * Kk)
#define OUT_LAB (2 * Bq * Kk + Bq * Kk * Dd)

using bf16x8 = __attribute__((ext_vector_type(8))) __bf16;
using f32x4  = __attribute__((ext_vector_type(4))) float;
using u16x8  = __attribute__((ext_vector_type(8))) unsigned short;
using u16x4  = __attribute__((ext_vector_type(4))) unsigned short;

__device__ __forceinline__ unsigned short f2bf(float f) {  // RNE f32->bf16
  unsigned u = __builtin_bit_cast(unsigned, f);
  return (unsigned short)((u + 0x7FFFu + ((u >> 16) & 1u)) >> 16);
}
__device__ __forceinline__ float bf2f(unsigned short b) {
  return __builtin_bit_cast(float, (unsigned)b << 16);
}

// async global->LDS, 16B per lane (dst must be wave-uniform base + lane*16)
#define GLD16(gp, lp)                                                   \
  __builtin_amdgcn_global_load_lds(                                     \
      (const __attribute__((address_space(1))) unsigned int*)(gp),      \
      (__attribute__((address_space(3))) unsigned int*)(lp), 16, 0, 0)

// ---------------------------------------------------------------------------
// Kernel 1: L2-normalize queries -> bf16, pre-swizzled for LDS A-tile.
// ---------------------------------------------------------------------------
__global__ __launch_bounds__(256) void k_norm(const float* __restrict__ q,
                                              unsigned short* __restrict__ qb) {
  const int row = blockIdx.x;
  const int t = threadIdx.x;
  const float v0 = q[row * Dd + t];
  const float v1 = q[row * Dd + t + 256];
  float ss = v0 * v0 + v1 * v1;
#pragma unroll
  for (int m = 32; m >= 1; m >>= 1) ss += __shfl_xor(ss, m);
  __shared__ float wsum[4];
  if ((t & 63) == 0) wsum[t >> 6] = ss;
  __syncthreads();
  const float inv = rsqrtf(wsum[0] + wsum[1] + wsum[2] + wsum[3]);
  const int r7 = row & 7;
  const int k0 = t;
  const int p0 = (k0 & ~0x38) | ((((k0 >> 3) & 7) ^ r7) << 3);
  qb[row * Dd + p0] = f2bf(v0 * inv);
  const int k1 = t + 256;
  const int p1 = (k1 & ~0x38) | ((((k1 >> 3) & 7) ^ r7) << 3);
  qb[row * Dd + p1] = f2bf(v1 * inv);
}

// ---------------------------------------------------------------------------
// Kernel 2: bf16 MFMA GEMM (unchanged from R1): sims[chunk rows][N] bf16,
// lane-permuted cols. 256x128 tile, 4 waves, mfma_f32_16x16x32_bf16.
// ---------------------------------------------------------------------------
__global__ __launch_bounds__(256, 2) void k_gemm(
    const unsigned short* __restrict__ qb, const float* __restrict__ w,
    unsigned short* __restrict__ sims, int m0) {
  __shared__ __align__(16) unsigned short As[256 * 64];  // 32 KB
  __shared__ __align__(16) unsigned short Bs[128 * 72];  // 18 KB (pad+swz)
  const int t = threadIdx.x;
  const int l = t & 63;
  const int wv = t >> 6;
  const int m = l & 15;
  const int g = l >> 4;
  const int rowg = wv >> 1;
  const int colg = wv & 1;
  const int rb = m0 + blockIdx.x * 256;
  const int n0 = blockIdx.y * 128;
  const int ct = t & 31, dt = t >> 5;

  f32x4 acc[8][4] = {};

  for (int kt = 0; kt < 8; kt++) {
    __syncthreads();
#pragma unroll
    for (int p = 0; p < 8; p++) {
      const int i = p * 256 + t;
      const int r = i >> 3, c = i & 7;
      GLD16(qb + (size_t)(rb + r) * Dd + kt * 64 + c * 8, &As[i * 8]);
    }
    {
      const float* src = w + (size_t)(kt * 64 + dt * 8) * Nn + n0 + ct * 4;
#pragma unroll
      for (int h = 0; h < 2; h++) {
        f32x4 f0 = *(const f32x4*)(src + (size_t)(h * 4 + 0) * Nn);
        f32x4 f1 = *(const f32x4*)(src + (size_t)(h * 4 + 1) * Nn);
        f32x4 f2 = *(const f32x4*)(src + (size_t)(h * 4 + 2) * Nn);
        f32x4 f3 = *(const f32x4*)(src + (size_t)(h * 4 + 3) * Nn);
#pragma unroll
        for (int j = 0; j < 4; j++) {
          const int col = ct * 4 + j;
          unsigned* dst =
              (unsigned*)&Bs[col * 72 + ((dt * 8) ^ ((ct & 7) << 3))];
          dst[h * 2 + 0] =
              (unsigned)f2bf(f0[j]) | ((unsigned)f2bf(f1[j]) << 16);
          dst[h * 2 + 1] =
              (unsigned)f2bf(f2[j]) | ((unsigned)f2bf(f3[j]) << 16);
        }
      }
    }
    __syncthreads();
#pragma unroll
    for (int ks = 0; ks < 2; ks++) {
      bf16x8 b[4];
#pragma unroll
      for (int cf = 0; cf < 4; cf++) {
        const int col = colg * 64 + cf * 16 + m;
        const int kpos = (ks * 32 + g * 8) ^ (((col >> 2) & 7) << 3);
        b[cf] = *(const bf16x8*)&Bs[col * 72 + kpos];
      }
#pragma unroll
      for (int rf = 0; rf < 8; rf++) {
        const int row = rowg * 128 + rf * 16 + m;
        const int cc = (ks * 4 + g) ^ (row & 7);
        const bf16x8 a = *(const bf16x8*)&As[row * 64 + cc * 8];
#pragma unroll
        for (int cf = 0; cf < 4; cf++)
          acc[rf][cf] = __builtin_amdgcn_mfma_f32_16x16x32_bf16(
              a, b[cf], acc[rf][cf], 0, 0, 0);
      }
    }
  }
#pragma unroll
  for (int rf = 0; rf < 8; rf++)
#pragma unroll
    for (int r = 0; r < 4; r++) {
      const int srow = blockIdx.x * 256 + rowg * 128 + rf * 16 + g * 4 + r;
      u16x4 v = {f2bf(acc[rf][0][r]), f2bf(acc[rf][1][r]),
                 f2bf(acc[rf][2][r]), f2bf(acc[rf][3][r])};
      *(u16x4*)&sims[(size_t)srow * Nn + n0 + colg * 64 + m * 4] = v;
    }
}

// ---------------------------------------------------------------------------
// Kernel 3 (unchanged): per-row streaming per-lane top-8 over bf16 sims.
// ---------------------------------------------------------------------------
__global__ __launch_bounds__(256) void k_select(
    const unsigned short* __restrict__ sims, float* __restrict__ cs,
    int* __restrict__ ci, int m0) {
  const int srow = blockIdx.x;
  const int row = m0 + srow;
  const int t = threadIdx.x;
  const unsigned short* base = sims + (size_t)srow * Nn;
  float s[8];
  int ix[8];
#pragma unroll
  for (int q2 = 0; q2 < 8; q2++) { s[q2] = -INFINITY; ix[q2] = 0; }
  float mn = -INFINITY;
#pragma unroll 2
  for (int it = 0; it < Nn / 2048; it++) {
    const int off = it * 2048 + t * 8;
    const u16x8 v = *(const u16x8*)(base + off);
    float f[8];
#pragma unroll
    for (int j = 0; j < 8; j++) f[j] = bf2f(v[j]);
    const float vm = fmaxf(fmaxf(fmaxf(f[0], f[1]), fmaxf(f[2], f[3])),
                           fmaxf(fmaxf(f[4], f[5]), fmaxf(f[6], f[7])));
    if (vm > mn) {
#pragma unroll
      for (int j = 0; j < 8; j++) {
        if (f[j] > mn) {
          float cm = s[0];
          int cp = 0;
#pragma unroll
          for (int q2 = 1; q2 < 8; q2++)
            if (s[q2] < cm) { cm = s[q2]; cp = q2; }
#pragma unroll
          for (int q2 = 0; q2 < 8; q2++)
            if (q2 == cp) { s[q2] = f[j]; ix[q2] = off + j; }
          mn = s[0];
#pragma unroll
          for (int q2 = 1; q2 < 8; q2++) mn = fminf(mn, s[q2]);
        }
      }
    }
  }
#pragma unroll
  for (int q2 = 0; q2 < 8; q2++) {
    const int cp = ix[q2];
    const int b7 = cp & 127;
    const int col = (cp & ~127) + ((b7 >> 6) << 6) + ((b7 & 3) << 4) + ((b7 >> 2) & 15);
    cs[(size_t)row * CPR + t * 8 + q2] = s[q2];
    ci[(size_t)row * CPR + t * 8 + q2] = col;
  }
}

// ---------------------------------------------------------------------------
// Kernel 3.5 (NEW): tiled transpose w [D][N] fp32 -> wT [N][D] fp32.
// 64x64 tiles via LDS (pad 65 -> conflict-free scatter), float4 in/out.
// wT overlays the (dead) sims buffer: both are exactly 268.4 MB.
// ---------------------------------------------------------------------------
__global__ __launch_bounds__(256) void k_transpose(const float* __restrict__ w,
                                                   float* __restrict__ wT) {
  __shared__ float tile[64][65];
  const int t = threadIdx.x;
  const int nbase = blockIdx.x * 64;
  const int dbase = blockIdx.y * 64;
  const int tn4 = (t & 15) * 4;  // n within tile (float4)
  const int dr = t >> 4;         // d row 0..15
#pragma unroll
  for (int p = 0; p < 4; p++) {
    const int d = p * 16 + dr;
    const f32x4 v = *(const f32x4*)&w[(size_t)(dbase + d) * Nn + nbase + tn4];
    tile[tn4 + 0][d] = v[0];
    tile[tn4 + 1][d] = v[1];
    tile[tn4 + 2][d] = v[2];
    tile[tn4 + 3][d] = v[3];
  }
  __syncthreads();
  const int wn = t >> 4;         // n row 0..15
  const int wd0 = (t & 15) * 4;  // d within tile (float4)
#pragma unroll
  for (int p = 0; p < 4; p++) {
    const int n = p * 16 + wn;
    const f32x4 v = {tile[n][wd0], tile[n][wd0 + 1], tile[n][wd0 + 2],
                     tile[n][wd0 + 3]};
    *(f32x4*)&wT[(size_t)(nbase + n) * Dd + dbase + wd0] = v;
  }
}

// ---------------------------------------------------------------------------
// Kernel 4: per row — wave 0 top-32 extraction; f64 rescore; sorted top-16;
// gather. TR=true reads candidate columns from wT [N][D] (coalesced rows,
// same fp32 bits -> bit-identical results). TR=false is the legacy
// column-strided fallback for small workspaces.
// ---------------------------------------------------------------------------
template <bool TR>
__global__ __launch_bounds__(256) void k_final(
    const float* __restrict__ cs, const int* __restrict__ ci,
    const float* __restrict__ label, const float* __restrict__ w,
    const float* __restrict__ wT, const float* __restrict__ q,
    float* __restrict__ out) {
  const int row = blockIdx.x;
  const int t = threadIdx.x;
  const int lane = t & 63;
  const int wv = t >> 6;

  __shared__ float shs[CPR];
  __shared__ int shi[CPR];
  __shared__ int sel[Mm];
  __shared__ double resc[Mm];
  __shared__ int sel16[Kk];

#pragma unroll
  for (int j = 0; j < CPR / 256; j++) {
    const int c = j * 256 + t;
    shs[c] = cs[row * CPR + c];
    shi[c] = ci[row * CPR + c] & (Nn - 1);
  }
  __syncthreads();

  // ---- stage 1: wave 0 extracts top-32 (exact) ----
  if (t < 64) {
    const int seg = t * (CPR / 64);
    float bs = -INFINITY;
    int bi = 0x7fffffff;
    int bp = seg;
    for (int p = seg; p < seg + CPR / 64; p++) {
      const float v = shs[p];
      const int ix = shi[p];
      if (v > bs || (v == bs && ix < bi)) { bs = v; bi = ix; bp = p; }
    }
#pragma unroll 1
    for (int it = 0; it < Mm; it++) {
      float s = bs;
      int si = bi;
      int sl = t;
#pragma unroll
      for (int mk = 32; mk >= 1; mk >>= 1) {
        const float so = __shfl_xor(s, mk);
        const int io = __shfl_xor(si, mk);
        const int lo = __shfl_xor(sl, mk);
        if (so > s || (so == s && (io < si || (io == si && lo < sl)))) {
          s = so; si = io; sl = lo;
        }
      }
      if (t == 0) sel[it] = si & (Nn - 1);
      if (t == sl) {
        shs[bp] = -INFINITY;
        bs = -INFINITY;
        bi = 0x7fffffff;
        bp = seg;
        for (int p = seg; p < seg + CPR / 64; p++) {
          const float v = shs[p];
          const int ix = shi[p];
          if (v > bs || (v == bs && ix < bi)) { bs = v; bi = ix; bp = p; }
        }
      }
    }
  }
  __syncthreads();

  // ---- stage 2: per-lane f64 q-slice + per-wave redundant norm ----
  double qd[8];
#pragma unroll
  for (int j = 0; j < 8; j++) qd[j] = (double)q[row * Dd + lane * 8 + j];
  double nn = 0.0;
#pragma unroll
  for (int j = 0; j < 8; j++) nn += qd[j] * qd[j];
#pragma unroll
  for (int mk = 32; mk >= 1; mk >>= 1) nn += __shfl_xor(nn, mk);
  const double nrm = sqrt(nn);

  // ---- stage 3: wave wv rescores 8 candidates in f64 ----
#pragma unroll 1
  for (int i = 0; i < Mm / 4; i++) {
    const int c = wv * (Mm / 4) + i;
    const int idx = sel[c];
    double d = 0.0;
    if (TR) {
      const float* wr = wT + (size_t)idx * Dd + lane * 8;
      const f32x4 wa = *(const f32x4*)wr;
      const f32x4 wb = *(const f32x4*)(wr + 4);
#pragma unroll
      for (int j = 0; j < 4; j++) d += qd[j] * (double)wa[j];
#pragma unroll
      for (int j = 0; j < 4; j++) d += qd[4 + j] * (double)wb[j];
    } else {
#pragma unroll
      for (int j = 0; j < 8; j++)
        d += qd[j] * (double)w[(size_t)(lane * 8 + j) * Nn + idx];
    }
#pragma unroll
    for (int mk = 32; mk >= 1; mk >>= 1) d += __shfl_xor(d, mk);
    if (lane == 0) resc[c] = d / nrm;
  }
  __syncthreads();

  // ---- stage 4: wave 0: sorted top-16 of 32 f64 scores ----
  float* out_sc = out + OUT_SC;
  float* out_ix = out + OUT_IDX;
  float* out_sq = out + OUT_SEQ;
  float* out_lb = out + OUT_LAB;
  if (t < 64) {
    double s = (t < Mm) ? resc[t] : -INFINITY;
    int ix = (t < Mm) ? sel[t] : 0x7fffffff;
#pragma unroll 1
    for (int it = 0; it < Kk; it++) {
      double bs2 = s;
      int bi2 = ix;
      int bl = t;
#pragma unroll
      for (int mk = 32; mk >= 1; mk >>= 1) {
        const double so = __shfl_xor(bs2, mk);
        const int io = __shfl_xor(bi2, mk);
        const int lo = __shfl_xor(bl, mk);
        if (so > bs2 || (so == bs2 && (io < bi2 || (io == bi2 && lo < bl)))) {
          bs2 = so; bi2 = io; bl = lo;
        }
      }
      if (t == 0) {
        const int safe = bi2 & (Nn - 1);
        out_sc[row * Kk + it] = (float)bs2;
        out_ix[row * Kk + it] = (float)bi2;
        out_lb[row * Kk + it] = label[safe];
        sel16[it] = safe;
      }
      if (t == bl) { s = -INFINITY; ix = 0x7fffffff; }
    }
  }
  __syncthreads();

  // ---- stage 5: gather the 16 winning weight columns ----
#pragma unroll 1
  for (int j = 0; j < Kk; j++) {
    const int idx = sel16[j];
    if (TR) {
      out_sq[(size_t)(row * Kk + j) * Dd + t] = wT[(size_t)idx * Dd + t];
      out_sq[(size_t)(row * Kk + j) * Dd + t + 256] =
          wT[(size_t)idx * Dd + t + 256];
    } else {
      out_sq[(size_t)(row * Kk + j) * Dd + t] = w[(size_t)t * Nn + idx];
      out_sq[(size_t)(row * Kk + j) * Dd + t + 256] =
          w[(size_t)(t + 256) * Nn + idx];
    }
  }
}

// ---------------------------------------------------------------------------
extern "C" void kernel_launch(void* const* d_in, const int* in_sizes, int n_in,
                              void* d_out, int out_size, void* d_ws,
                              size_t ws_size, hipStream_t stream) {
  const float* q = (const float*)d_in[0];
  const float* w = (const float*)d_in[1];
  const float* lab = (const float*)d_in[2];
  float* out = (float*)d_out;

  // workspace: qb bf16 swz (1 MB) | cs (8 MB) | ci (8 MB) |
  //            shared region: sims bf16 chunk, then overlaid by wT fp32
  unsigned short* qb = (unsigned short*)d_ws;
  float* cs = (float*)((char*)d_ws + (size_t)Bq * Dd * 2);
  int* ci = (int*)(cs + (size_t)Bq * CPR);
  unsigned short* sims = (unsigned short*)(ci + (size_t)Bq * CPR);
  float* wT = (float*)sims;  // 131072*512*4 B == 1024*131072*2 B

  const size_t fixed = (size_t)Bq * Dd * 2 + (size_t)Bq * CPR * 8;
  const size_t big = (size_t)Nn * Dd * 4;  // 268.4 MB

  k_norm<<<Bq, 256, 0, stream>>>(q, qb);
  if (ws_size >= fixed + big) {
    // full-speed path: chunk=1024 GEMM, then transpose into dead sims buffer
    k_gemm<<<dim3(Bq / 256, Nn / 128), 256, 0, stream>>>(qb, w, sims, 0);
    k_select<<<Bq, 256, 0, stream>>>(sims, cs, ci, 0);
    k_transpose<<<dim3(Nn / 64, Dd / 64), 256, 0, stream>>>(w, wT);
    k_final<true><<<Bq, 256, 0, stream>>>(cs, ci, lab, w, wT, q, out);
  } else {
    int chunk = 256;
    if (ws_size >= fixed + (size_t)512 * Nn * 2) chunk = 512;
    for (int m0 = 0; m0 < Bq; m0 += chunk) {
      k_gemm<<<dim3(chunk / 256, Nn / 128), 256, 0, stream>>>(qb, w, sims, m0);
      k_select<<<chunk, 256, 0, stream>>>(sims, cs, ci, m0);
    }
    k_final<false><<<Bq, 256, 0, stream>>>(cs, ci, lab, w, wT, q, out);
  }
}